// Round 15
// baseline (681.175 us; speedup 1.0000x reference)
//
#include <hip/hip_runtime.h>
#include <math.h>

// DenseCaps dynamic routing, MI355X. B=32, I=4096, O=32, 4x4 poses, 3 iters.
// R14 budget re-audit (R1's measured 51.6us pass x3 + gaps = 210 exactly):
// fills are OUTSIDE the timed window; dur = 3*pass(~33) + 3*reduce(~5) +
// gaps(~12). Pass internals are saturated (7 variants, 33-51us each). Last
// lever: dispatch count. This round fuses each reduce into the pass kernel's
// tail: ticket atomicAdd after __threadfence(); the LAST 64 blocks (grid
// 1024 fully co-resident: 4/CU needed, 6/CU LDS capacity -> deadlock-free)
// spin on acquire-load then reduce a 256-element slice. Non-gate blocks
// retire (no R13 grid.sync). Pass-indexed partial buffers (3x16.8MB) keep
// gate reads first-touch; 12B ticket memset per launch (graph-safe).
// 4 dispatches total (memset + 3 passes).

#define NB 32
#define NI 4096
#define NO 32
#define I_TILE 16
#define NCHUNK (NI / I_TILE)        // 256
#define B_TILE 8
#define NBG (NB / B_TILE)           // 4
#define GRID_N (NCHUNK * NBG)       // 1024 blocks per pass
#define GATES 64                    // last-64 blocks do the reduce
#define SOFF (NB * NO * 16)         // 16384 floats per (chunk) partial slab
#define PBUF ((size_t)NCHUNK * SOFF)// floats per pass partial buffer
#define EPSF 1e-12f

#define W_OSTR 10                   // words per o-row: 8 data + 2 pad
#define W_ISTR (32 * W_OSTR)        // 320 words per i-slab
#define W_WORDS (I_TILE * W_ISTR)   // 5120 words = 20 KB
#define P_WORDS (B_TILE * I_TILE * 8) // 1024 words = 4 KB

typedef _Float16 v2h __attribute__((ext_vector_type(2)));

#if __has_builtin(__builtin_amdgcn_fdot2)
__device__ __forceinline__ float fdot2(v2h a, v2h b, float c) {
    return __builtin_amdgcn_fdot2(a, b, c, false);
}
#else
__device__ __forceinline__ float fdot2(v2h a, v2h b, float c) {
    return fmaf((float)a.x, (float)b.x, fmaf((float)a.y, (float)b.y, c));
}
#endif

#if __has_builtin(__builtin_amdgcn_cvt_pkrtz)
__device__ __forceinline__ v2h pk2h(float a, float b) {
    return __builtin_bit_cast(v2h, __builtin_amdgcn_cvt_pkrtz(a, b));
}
#else
__device__ __forceinline__ v2h pk2h(float a, float b) {
    v2h r; r.x = (_Float16)a; r.y = (_Float16)b; return r;
}
#endif

__device__ __forceinline__ v2h bch(unsigned u) {
    return __builtin_bit_cast(v2h, u);
}

__device__ __forceinline__ float dot4(const float4 a, const float4 b) {
    return fmaf(a.x, b.x, fmaf(a.y, b.y, fmaf(a.z, b.z, a.w * b.w)));
}

__device__ __forceinline__ void fma4(float4& s, const float c, const float4 t) {
    s.x = fmaf(c, t.x, s.x);
    s.y = fmaf(c, t.y, s.y);
    s.z = fmaf(c, t.z, s.z);
    s.w = fmaf(c, t.w, s.w);
}

template <int CTRL>
__device__ __forceinline__ float dpp_add(float x) {
    int xi = __builtin_bit_cast(int, x);
    int yi = __builtin_amdgcn_update_dpp(0, xi, CTRL, 0xf, 0xf, false);
    return x + __builtin_bit_cast(float, yi);
}

// sum over each 32-lane half (the o-group)
__device__ __forceinline__ float sum32(float x) {
    x = dpp_add<0xB1>(x);    // xor1
    x = dpp_add<0x4E>(x);    // xor2
    x = dpp_add<0x141>(x);   // xor7 (8-group done)
    x = dpp_add<0x140>(x);   // xor15 (16-row done)
#if __has_builtin(__builtin_amdgcn_permlane16_swap)
    typedef unsigned uv2 __attribute__((ext_vector_type(2)));
    const unsigned xi = __builtin_bit_cast(unsigned, x);
    uv2 r = __builtin_amdgcn_permlane16_swap(xi, xi, false, false);
    return __builtin_bit_cast(float, r.x) + __builtin_bit_cast(float, r.y);
#else
    int t = __builtin_amdgcn_ds_swizzle(__builtin_bit_cast(int, x), 0x401F);
    return x + __builtin_bit_cast(float, t);
#endif
}

// gate reduce: one element eg = bo*16 + k; eg&15 must equal lane&15.
__device__ __forceinline__ void gate_reduce(
    const float* __restrict__ sp, float* __restrict__ v_buf,
    float* __restrict__ out, const int eg, const int pass)
{
    float acc = 0.0f;
    #pragma unroll 8
    for (int c = 0; c < NCHUNK; ++c)
        acc += sp[(size_t)c * SOFF + eg];
    float x = acc * acc;
    #pragma unroll
    for (int msk = 8; msk >= 1; msk >>= 1)
        x += __shfl_xor(x, msk, 16);
    const float n2 = x;
    const float n  = sqrtf(n2 + EPSF);
    const float sc = (n2 / (1.0f + n2)) / n;
    if (pass < 2) {
        const float vold = (pass == 0) ? 0.0f : v_buf[eg];
        v_buf[eg] = fmaf(sc, acc, vold);
    } else {
        out[eg] = sc * acc;
        if ((eg & 15) == 0)
            out[NB * NO * 16 + (eg >> 4)] = sqrtf(n2 * sc * sc + EPSF);
    }
}

// ---------------- pass kernel with fused gate-reduce tail ----------------
__global__ __launch_bounds__(256, 4) void caps_pass_h(
    const float* __restrict__ poses, const float* __restrict__ w,
    float* __restrict__ v_buf, float* __restrict__ s_part3,
    float* __restrict__ out, unsigned* __restrict__ cnt, const int pass)
{
    __shared__ unsigned wsw[W_WORDS];   // 20480 B
    __shared__ unsigned psw[P_WORDS];   //  4096 B
    __shared__ int gate_s;
    const int tid    = threadIdx.x;
    const int chunk  = blockIdx.x;
    const int bgroup = blockIdx.y;
    const int ibase  = chunk * I_TILE;
    float* s_part = s_part3 + (size_t)pass * PBUF;

    // ---- stage w: f32 -> f16 pairs, coalesced ----
    #pragma unroll
    for (int r = 0; r < 4; ++r) {
        const int idx = r * 256 + tid;       // 0..1023 -> (o, i, m)
        const int o_l = idx >> 5;
        const int l   = idx & 31;
        const int i_l = l >> 1;
        const int m   = l & 1;
        const float* g = w + (((size_t)o_l * NI + ibase + i_l) << 4) + (m << 3);
        const float4 A = *(const float4*)g;        // row y=2m
        const float4 B = *(const float4*)(g + 4);  // row y=2m+1
        const v2h c0 = pk2h(A.x, B.x), c1 = pk2h(A.y, B.y);
        const v2h c2 = pk2h(A.z, B.z), c3 = pk2h(A.w, B.w);
        const int base = i_l * W_ISTR + o_l * W_OSTR + (m << 2);
        *(uint2*)&wsw[base]     = make_uint2(__builtin_bit_cast(unsigned, c0),
                                             __builtin_bit_cast(unsigned, c1));
        *(uint2*)&wsw[base + 2] = make_uint2(__builtin_bit_cast(unsigned, c2),
                                             __builtin_bit_cast(unsigned, c3));
    }
    // ---- stage poses: f32 -> f16 pairs, coalesced ----
    #pragma unroll
    for (int r = 0; r < 2; ++r) {
        const int idx = r * 256 + tid;       // 0..511 -> (b, i, x)
        const int b_l = idx >> 6;
        const int l   = idx & 63;
        const int i_l = l >> 2;
        const int x   = l & 3;
        const float4 row = *(const float4*)(
            poses + (((size_t)(bgroup * B_TILE + b_l) * NI + ibase + i_l) << 4)
                  + (x << 2));
        const v2h c0 = pk2h(row.x, row.y), c1 = pk2h(row.z, row.w);
        *(uint2*)&psw[((b_l * I_TILE + i_l) << 3) + (x << 1)] =
            make_uint2(__builtin_bit_cast(unsigned, c0),
                       __builtin_bit_cast(unsigned, c1));
    }

    const int o    = tid & 31;
    const int bsub = tid >> 5;
    const int b    = bgroup * B_TILE + bsub;
    const int bo   = b * NO + o;

    float4 vv0 = {0,0,0,0}, vv1 = {0,0,0,0}, vv2 = {0,0,0,0}, vv3 = {0,0,0,0};
    if (pass > 0) {
        const float4* vp = (const float4*)(v_buf + (bo << 4));
        vv0 = vp[0]; vv1 = vp[1]; vv2 = vp[2]; vv3 = vp[3];
    }

    const unsigned* wrow = &wsw[o * W_OSTR];
    const unsigned* prow = &psw[(bsub * I_TILE) << 3];

    __syncthreads();

    float4 s0 = {0,0,0,0}, s1 = {0,0,0,0}, s2 = {0,0,0,0}, s3 = {0,0,0,0};

    #pragma unroll 2
    for (int i = 0; i < I_TILE; ++i) {
        const uint2 wa = *(const uint2*)&wrow[i * W_ISTR + 0];
        const uint2 wb = *(const uint2*)&wrow[i * W_ISTR + 2];
        const uint2 wc = *(const uint2*)&wrow[i * W_ISTR + 4];
        const uint2 wd = *(const uint2*)&wrow[i * W_ISTR + 6];
        const uint4 pa = *(const uint4*)&prow[(i << 3) + 0];
        const uint4 pb = *(const uint4*)&prow[(i << 3) + 4];

        const v2h p00 = bch(pa.x), p01 = bch(pa.y);   // x0: y01, y23
        const v2h p10 = bch(pa.z), p11 = bch(pa.w);   // x1
        const v2h p20 = bch(pb.x), p21 = bch(pb.y);   // x2
        const v2h p30 = bch(pb.z), p31 = bch(pb.w);   // x3
        const v2h w00 = bch(wa.x), w01 = bch(wa.y);   // m0: z0, z1
        const v2h w02 = bch(wb.x), w03 = bch(wb.y);   // m0: z2, z3
        const v2h w10 = bch(wc.x), w11 = bch(wc.y);   // m1: z0, z1
        const v2h w12 = bch(wd.x), w13 = bch(wd.y);   // m1: z2, z3

        float4 t0, t1, t2, t3;   // votes[x][z] = sum_y P[x][y] W[y][z]
        t0.x = fdot2(p00, w00, fdot2(p01, w10, 0.0f));
        t0.y = fdot2(p00, w01, fdot2(p01, w11, 0.0f));
        t0.z = fdot2(p00, w02, fdot2(p01, w12, 0.0f));
        t0.w = fdot2(p00, w03, fdot2(p01, w13, 0.0f));
        t1.x = fdot2(p10, w00, fdot2(p11, w10, 0.0f));
        t1.y = fdot2(p10, w01, fdot2(p11, w11, 0.0f));
        t1.z = fdot2(p10, w02, fdot2(p11, w12, 0.0f));
        t1.w = fdot2(p10, w03, fdot2(p11, w13, 0.0f));
        t2.x = fdot2(p20, w00, fdot2(p21, w10, 0.0f));
        t2.y = fdot2(p20, w01, fdot2(p21, w11, 0.0f));
        t2.z = fdot2(p20, w02, fdot2(p21, w12, 0.0f));
        t2.w = fdot2(p20, w03, fdot2(p21, w13, 0.0f));
        t3.x = fdot2(p30, w00, fdot2(p31, w10, 0.0f));
        t3.y = fdot2(p30, w01, fdot2(p31, w11, 0.0f));
        t3.z = fdot2(p30, w02, fdot2(p31, w12, 0.0f));
        t3.w = fdot2(p30, w03, fdot2(p31, w13, 0.0f));

        float cc;
        if (pass == 0) {
            cc = 1.0f / 32.0f;
        } else {
            const float d = dot4(t0,vv0) + dot4(t1,vv1)
                          + dot4(t2,vv2) + dot4(t3,vv3);
            const float e  = __expf(d);
            const float es = sum32(e);
            cc = __fdividef(e, es);
        }
        fma4(s0, cc, t0); fma4(s1, cc, t1);
        fma4(s2, cc, t2); fma4(s3, cc, t3);
    }

    // deterministic partial store: [chunk][bo][16]
    float4* sp = (float4*)(s_part + ((size_t)chunk * (NB * NO) + bo) * 16);
    sp[0] = s0; sp[1] = s1; sp[2] = s2; sp[3] = s3;

    // ---- publish + ticket; last GATES blocks reduce ----
    __threadfence();        // device-scope: partials visible across XCDs
    __syncthreads();        // all threads' stores+fences done
    if (tid == 0) {
        const unsigned old = __hip_atomic_fetch_add(
            &cnt[pass], 1u, __ATOMIC_ACQ_REL, __HIP_MEMORY_SCOPE_AGENT);
        gate_s = (old >= (unsigned)(GRID_N - GATES))
               ? (int)(old - (GRID_N - GATES)) : -1;
    }
    __syncthreads();
    const int gate = gate_s;
    if (gate >= 0) {
        // all 1024 blocks are co-resident (4/CU needed, 6/CU LDS capacity)
        // -> every block will tick; spin terminates.
        while (__hip_atomic_load(&cnt[pass], __ATOMIC_ACQUIRE,
                                 __HIP_MEMORY_SCOPE_AGENT) < (unsigned)GRID_N) {
#if __has_builtin(__builtin_amdgcn_s_sleep)
            __builtin_amdgcn_s_sleep(1);
#endif
        }
        gate_reduce(s_part, v_buf, out, (gate << 8) + tid, pass);
    }
}

// ---------------- fallback: R14 two-kernel path (tiny ws) -----------------
__global__ __launch_bounds__(256, 4) void caps_pass_nf(
    const float* __restrict__ poses, const float* __restrict__ w,
    const float* __restrict__ v_buf, float* __restrict__ s_part,
    const int pass)
{
    // identical body minus gate tail, partials into single buffer
    __shared__ unsigned wsw[W_WORDS];
    __shared__ unsigned psw[P_WORDS];
    const int tid    = threadIdx.x;
    const int chunk  = blockIdx.x;
    const int bgroup = blockIdx.y;
    const int ibase  = chunk * I_TILE;

    #pragma unroll
    for (int r = 0; r < 4; ++r) {
        const int idx = r * 256 + tid;
        const int o_l = idx >> 5;
        const int l   = idx & 31;
        const int i_l = l >> 1;
        const int m   = l & 1;
        const float* g = w + (((size_t)o_l * NI + ibase + i_l) << 4) + (m << 3);
        const float4 A = *(const float4*)g;
        const float4 B = *(const float4*)(g + 4);
        const v2h c0 = pk2h(A.x, B.x), c1 = pk2h(A.y, B.y);
        const v2h c2 = pk2h(A.z, B.z), c3 = pk2h(A.w, B.w);
        const int base = i_l * W_ISTR + o_l * W_OSTR + (m << 2);
        *(uint2*)&wsw[base]     = make_uint2(__builtin_bit_cast(unsigned, c0),
                                             __builtin_bit_cast(unsigned, c1));
        *(uint2*)&wsw[base + 2] = make_uint2(__builtin_bit_cast(unsigned, c2),
                                             __builtin_bit_cast(unsigned, c3));
    }
    #pragma unroll
    for (int r = 0; r < 2; ++r) {
        const int idx = r * 256 + tid;
        const int b_l = idx >> 6;
        const int l   = idx & 63;
        const int i_l = l >> 2;
        const int x   = l & 3;
        const float4 row = *(const float4*)(
            poses + (((size_t)(bgroup * B_TILE + b_l) * NI + ibase + i_l) << 4)
                  + (x << 2));
        const v2h c0 = pk2h(row.x, row.y), c1 = pk2h(row.z, row.w);
        *(uint2*)&psw[((b_l * I_TILE + i_l) << 3) + (x << 1)] =
            make_uint2(__builtin_bit_cast(unsigned, c0),
                       __builtin_bit_cast(unsigned, c1));
    }

    const int o    = tid & 31;
    const int bsub = tid >> 5;
    const int b    = bgroup * B_TILE + bsub;
    const int bo   = b * NO + o;

    float4 vv0 = {0,0,0,0}, vv1 = {0,0,0,0}, vv2 = {0,0,0,0}, vv3 = {0,0,0,0};
    if (pass > 0) {
        const float4* vp = (const float4*)(v_buf + (bo << 4));
        vv0 = vp[0]; vv1 = vp[1]; vv2 = vp[2]; vv3 = vp[3];
    }
    const unsigned* wrow = &wsw[o * W_OSTR];
    const unsigned* prow = &psw[(bsub * I_TILE) << 3];
    __syncthreads();

    float4 s0 = {0,0,0,0}, s1 = {0,0,0,0}, s2 = {0,0,0,0}, s3 = {0,0,0,0};
    #pragma unroll 2
    for (int i = 0; i < I_TILE; ++i) {
        const uint2 wa = *(const uint2*)&wrow[i * W_ISTR + 0];
        const uint2 wb = *(const uint2*)&wrow[i * W_ISTR + 2];
        const uint2 wc = *(const uint2*)&wrow[i * W_ISTR + 4];
        const uint2 wd = *(const uint2*)&wrow[i * W_ISTR + 6];
        const uint4 pa = *(const uint4*)&prow[(i << 3) + 0];
        const uint4 pb = *(const uint4*)&prow[(i << 3) + 4];
        const v2h p00 = bch(pa.x), p01 = bch(pa.y);
        const v2h p10 = bch(pa.z), p11 = bch(pa.w);
        const v2h p20 = bch(pb.x), p21 = bch(pb.y);
        const v2h p30 = bch(pb.z), p31 = bch(pb.w);
        const v2h w00 = bch(wa.x), w01 = bch(wa.y);
        const v2h w02 = bch(wb.x), w03 = bch(wb.y);
        const v2h w10 = bch(wc.x), w11 = bch(wc.y);
        const v2h w12 = bch(wd.x), w13 = bch(wd.y);
        float4 t0, t1, t2, t3;
        t0.x = fdot2(p00, w00, fdot2(p01, w10, 0.0f));
        t0.y = fdot2(p00, w01, fdot2(p01, w11, 0.0f));
        t0.z = fdot2(p00, w02, fdot2(p01, w12, 0.0f));
        t0.w = fdot2(p00, w03, fdot2(p01, w13, 0.0f));
        t1.x = fdot2(p10, w00, fdot2(p11, w10, 0.0f));
        t1.y = fdot2(p10, w01, fdot2(p11, w11, 0.0f));
        t1.z = fdot2(p10, w02, fdot2(p11, w12, 0.0f));
        t1.w = fdot2(p10, w03, fdot2(p11, w13, 0.0f));
        t2.x = fdot2(p20, w00, fdot2(p21, w10, 0.0f));
        t2.y = fdot2(p20, w01, fdot2(p21, w11, 0.0f));
        t2.z = fdot2(p20, w02, fdot2(p21, w12, 0.0f));
        t2.w = fdot2(p20, w03, fdot2(p21, w13, 0.0f));
        t3.x = fdot2(p30, w00, fdot2(p31, w10, 0.0f));
        t3.y = fdot2(p30, w01, fdot2(p31, w11, 0.0f));
        t3.z = fdot2(p30, w02, fdot2(p31, w12, 0.0f));
        t3.w = fdot2(p30, w03, fdot2(p31, w13, 0.0f));
        float cc;
        if (pass == 0) {
            cc = 1.0f / 32.0f;
        } else {
            const float d = dot4(t0,vv0) + dot4(t1,vv1)
                          + dot4(t2,vv2) + dot4(t3,vv3);
            const float e  = __expf(d);
            const float es = sum32(e);
            cc = __fdividef(e, es);
        }
        fma4(s0, cc, t0); fma4(s1, cc, t1);
        fma4(s2, cc, t2); fma4(s3, cc, t3);
    }
    float4* sp = (float4*)(s_part + ((size_t)chunk * (NB * NO) + bo) * 16);
    sp[0] = s0; sp[1] = s1; sp[2] = s2; sp[3] = s3;
}

__global__ __launch_bounds__(256) void caps_reduce_nf(
    const float* __restrict__ s_part, float* __restrict__ v_buf,
    float* __restrict__ out, const int pass)
{
    gate_reduce(s_part, v_buf, out, blockIdx.x * 256 + threadIdx.x, pass);
}

extern "C" void kernel_launch(void* const* d_in, const int* in_sizes, int n_in,
                              void* d_out, int out_size, void* d_ws, size_t ws_size,
                              hipStream_t stream) {
    const float* poses = (const float*)d_in[0];   // [B, I, 4, 4]
    // d_in[1] = input_activations — unused by the reference computation
    const float* w     = (const float*)d_in[2];   // [O, I, 4, 4]
    float* out = (float*)d_out;                   // [B,O,16] poses ++ [B,O] acts

    const size_t need = (3 * PBUF + SOFF) * sizeof(float) + 16;   // ~50.5 MB
    if (ws_size >= need) {
        float*    s_part3 = (float*)d_ws;         // [3][NCHUNK][B*O][16]
        float*    v_buf   = s_part3 + 3 * PBUF;
        unsigned* cnt     = (unsigned*)(v_buf + SOFF);
        (void)hipMemsetAsync(cnt, 0, 3 * sizeof(unsigned), stream);
        dim3 gp(NCHUNK, NBG), blk(256);
        for (int pass = 0; pass < 3; ++pass)
            caps_pass_h<<<gp, blk, 0, stream>>>(poses, w, v_buf, s_part3,
                                                out, cnt, pass);
    } else if (ws_size >= (PBUF + SOFF) * sizeof(float)) {
        // R14-equivalent two-kernel path
        float* s_part = (float*)d_ws;
        float* v_buf  = s_part + PBUF;
        dim3 gp(NCHUNK, NBG), blk(256), gr(64);
        for (int pass = 0; pass < 3; ++pass) {
            caps_pass_nf<<<gp, blk, 0, stream>>>(poses, w, v_buf, s_part, pass);
            caps_reduce_nf<<<gr, blk, 0, stream>>>(s_part, v_buf, out, pass);
        }
    }
}